// Round 7
// baseline (55797.821 us; speedup 1.0000x reference)
//
#include <hip/hip_runtime.h>
#include <math.h>

#define B_  32
#define T_  512
#define H_  512
#define A_  128
#define VD_ 512
#define V_  32000
#define GRID 512
#define NCHUNK 500   // 64-v logits chunks

__device__ __forceinline__ float sigf(float x){ return 1.f/(1.f+expf(-x)); }
__device__ __forceinline__ float dot4(float4 a, float4 b){ return a.x*b.x+a.y*b.y+a.z*b.z+a.w*b.w; }

struct DecArgs {
  const float *key, *value, *W_emb, *b_proj, *Wq, *bq, *W_ih, *W_hh, *b_ih, *b_hh, *Wm, *bm, *h00, *c00;
  const int* src_lens;
  float* out;
  float *hA, *hB, *c, *ctx, *en, *projT, *logits, *lse, *pm, *ps, *wqT;
  int *pidx, *idx;
  int* bar;   // [grp*32] 32 group counters, [1024] master, [1056] gen
  int L;
};

// ---------------- device-scope two-level grid barrier (512 blocks, 32 grp x 16)
__device__ __forceinline__ void gbar(int* bar) {
  __syncthreads();
  if (threadIdx.x == 0) {
    int* gen = bar + 1056;
    int g = __hip_atomic_load(gen, __ATOMIC_RELAXED, __HIP_MEMORY_SCOPE_AGENT);
    int grp = blockIdx.x & 31;
    int t = __hip_atomic_fetch_add(bar + grp*32, 1, __ATOMIC_ACQ_REL, __HIP_MEMORY_SCOPE_AGENT);
    bool rel = false;
    if (t == 15) {
      __hip_atomic_store(bar + grp*32, 0, __ATOMIC_RELAXED, __HIP_MEMORY_SCOPE_AGENT);
      int tm = __hip_atomic_fetch_add(bar + 1024, 1, __ATOMIC_ACQ_REL, __HIP_MEMORY_SCOPE_AGENT);
      if (tm == 31) {
        __hip_atomic_store(bar + 1024, 0, __ATOMIC_RELAXED, __HIP_MEMORY_SCOPE_AGENT);
        __hip_atomic_fetch_add(gen, 1, __ATOMIC_RELEASE, __HIP_MEMORY_SCOPE_AGENT);
        rel = true;
      }
    }
    if (!rel) {
      while (__hip_atomic_load(gen, __ATOMIC_ACQUIRE, __HIP_MEMORY_SCOPE_AGENT) == g)
        __builtin_amdgcn_s_sleep(1);
    }
  }
  __syncthreads();
}

// ---------------- P1: gates + LSTM cell (blocks 0..255; block covers 2 t-cols)
__device__ __forceinline__ void phase1(const DecArgs& P, const float* hin, float* hout,
                                       int bid, int tid, float* sf) {
  if (bid >= 256) return;
  int g = tid >> 6, tl = (tid >> 5) & 1, b = tid & 31;
  int t = bid*2 + tl;
  int j = g*512 + t;
  const float4* emb = (const float4*)(P.W_emb + (size_t)P.idx[b]*H_);
  const float4* cx  = (const float4*)(P.ctx + b*VD_);
  const float4* hv  = (const float4*)(hin + b*H_);
  const float4* wi  = (const float4*)(P.W_ih + (size_t)j*(H_+VD_));
  const float4* wc  = wi + 128;
  const float4* wh  = (const float4*)(P.W_hh + (size_t)j*H_);
  float acc = P.b_ih[j] + P.b_hh[j];
#pragma unroll 8
  for (int k = 0; k < 128; k++) acc += dot4(wi[k], emb[k]);
#pragma unroll 8
  for (int k = 0; k < 128; k++) acc += dot4(wc[k], cx[k]);
#pragma unroll 8
  for (int k = 0; k < 128; k++) acc += dot4(wh[k], hv[k]);
  sf[(tl*32 + b)*4 + g] = acc;
  __syncthreads();
  if (tid < 64) {
    int tl2 = tid >> 5, b2 = tid & 31;
    int t2 = bid*2 + tl2;
    float gi = sf[(tl2*32+b2)*4+0], gf = sf[(tl2*32+b2)*4+1];
    float gg = sf[(tl2*32+b2)*4+2], go = sf[(tl2*32+b2)*4+3];
    float c0 = P.c[b2*H_ + t2];
    float c1 = sigf(gf)*c0 + sigf(gi)*tanhf(gg);
    P.c[b2*H_ + t2] = c1;
    hout[b2*H_ + t2] = sigf(go)*tanhf(c1);
  }
}

// ---------------- P2: q (per-block from wqT) + energy t-slice -> en  (+out[sidx])
// block = ts*32 + b ; ts 0..15 owns t-range [ts*32, ts*32+32)
__device__ __forceinline__ void phase2(const DecArgs& P, const float* hsrc,
                                       int bid, int tid, float* smem, int sidx) {
  int b = bid & 31, ts = bid >> 5;
  float* h_sh = smem;          // 512
  float* qred = smem + 512;    // 256
  float* q_sh = smem + 768;    // 128
  float* red  = smem + 896;    // 256
  h_sh[tid]       = hsrc[b*H_ + tid];
  h_sh[tid + 256] = hsrc[b*H_ + tid + 256];
  __syncthreads();
  {
    int a = tid & 127, hf = tid >> 7;
    const float* wq = P.wqT + (size_t)hf*256*128 + a;   // wqT[k][a]
    float acc = 0.f;
#pragma unroll 8
    for (int k = 0; k < 256; k++) acc += h_sh[hf*256 + k] * wq[(size_t)k*128];
    qred[hf*128 + a] = acc;
  }
  __syncthreads();
  if (tid < 128) q_sh[tid] = qred[tid] + qred[128 + tid] + P.bq[tid];
  __syncthreads();
  {
    int tl = tid >> 3, ah = tid & 7;
    int t = ts*32 + tl;
    const float* kp = P.key + (size_t)b*A_*T_ + t;
    float e = 0.f;
#pragma unroll
    for (int j = 0; j < 16; j++) { int a = ah*16 + j; e += q_sh[a] * kp[(size_t)a*T_]; }
    red[tid] = e;
  }
  __syncthreads();
  if ((tid & 7) < 4) red[tid] += red[tid + 4];
  __syncthreads();
  if ((tid & 7) < 2) red[tid] += red[tid + 2];
  __syncthreads();
  if ((tid & 7) == 0) P.en[b*T_ + ts*32 + (tid >> 3)] = red[tid] + red[tid + 1];
  if (sidx >= 0) {
    float l = P.lse[b];
    const float4* lg = (const float4*)(P.logits + (size_t)b*V_ + ts*2000);
    float4* o4 = (float4*)(P.out + ((size_t)b*P.L + sidx)*V_ + ts*2000);
    for (int i = tid; i < 500; i += 256) {
      float4 x = lg[i];
      o4[i] = make_float4(x.x-l, x.y-l, x.z-l, x.w-l);
    }
  }
}

// ---------------- P3: masked softmax (from en) + ctx slice
__device__ __forceinline__ void phase3(const DecArgs& P, int bid, int tid, float* smem) {
  int b = bid & 31, vs = bid >> 5;
  float* e_sh = smem;          // 512
  float* att  = smem + 512;    // 512
  float* red  = smem + 1024;   // 256
  e_sh[tid]       = P.en[b*T_ + tid];
  e_sh[tid + 256] = P.en[b*T_ + tid + 256];
  __syncthreads();
  red[tid] = fmaxf(e_sh[tid], e_sh[tid + 256]);
  __syncthreads();
  for (int s2 = 128; s2 > 0; s2 >>= 1) { if (tid < s2) red[tid] = fmaxf(red[tid], red[tid+s2]); __syncthreads(); }
  float M = red[0];
  __syncthreads();
  int len = P.src_lens[b];
  float p0 = (tid       < len) ? expf(e_sh[tid] - M) : 0.f;
  float p1 = (tid + 256 < len) ? expf(e_sh[tid+256] - M) : 0.f;
  red[tid] = p0 + p1;
  __syncthreads();
  for (int s2 = 128; s2 > 0; s2 >>= 1) { if (tid < s2) red[tid] += red[tid+s2]; __syncthreads(); }
  float rS = 1.f / red[0];
  att[tid] = p0 * rS; att[tid + 256] = p1 * rS;
  __syncthreads();
  int vl = tid & 31, tq = tid >> 5;
  const float* vp = P.value + (size_t)b*T_*VD_ + vs*32 + vl;
  float acc = 0.f;
#pragma unroll 8
  for (int t = tq*64; t < tq*64 + 64; t++) acc += att[t] * vp[(size_t)t*VD_];
  red[tid] = acc;
  __syncthreads();
  if (tid < 32) {
    float s = 0.f;
#pragma unroll
    for (int j = 0; j < 8; j++) s += red[j*32 + tid];
    P.ctx[b*VD_ + vs*32 + tid] = s;
  }
}

// ---------------- P4: projT[m*32+b] = leaky_relu([c1,ctx1]@Wm[m] + bm)  (blocks 0..63)
__device__ __forceinline__ void phase4(const DecArgs& P, int bid, int tid) {
  if (bid < 64) {
    int m = bid*8 + (tid>>5), b = tid & 31;
    const float4* cv = (const float4*)(P.c + b*H_);
    const float4* xv = (const float4*)(P.ctx + b*VD_);
    const float4* wa = (const float4*)(P.Wm + (size_t)m*(H_+VD_));
    const float4* wb = wa + 128;
    float acc = P.bm[m];
#pragma unroll 8
    for (int k = 0; k < 128; k++) acc += dot4(wa[k], cv[k]);
#pragma unroll 8
    for (int k = 0; k < 128; k++) acc += dot4(wb[k], xv[k]);
    P.projT[m*32 + b] = (acc > 0.f) ? acc : 0.01f*acc;
  }
}

// ---------------- P5: logits chunk (64 v) register-tiled GEMM + online partials
// thread = (kp 0..7, vg 0..7, bg 0..3); 8v x 8b tile per thread, k split 8 ways
__device__ __forceinline__ void phase5(const DecArgs& P, int bid, int tid, float* sm) {
  if (bid >= NCHUNK) return;
  const int v0 = bid * 64;
  float* Wl   = sm;            // [64k][68] = 4352
  float* pl   = sm + 4352;     // [64k][32] = 2048
  float* part = sm + 6400;     // [32b][68] = 2176
  const int kp = tid >> 5, vg = (tid >> 2) & 7, bg = tid & 3;
  const int sr = tid >> 2, skq = tid & 3;   // staging: row 0..63, k-quarter 0..3
  float acc[64];
#pragma unroll
  for (int i = 0; i < 64; i++) acc[i] = 0.f;

  for (int w = 0; w < 8; w++) {
    __syncthreads();
    // stage: 4 independent coalesced float4 W-loads + 2 projT loads per thread
    const float* wsrc = P.W_emb + (size_t)(v0 + sr)*H_ + w*64 + skq*16;
    float4 t0 = *((const float4*)(wsrc + 0));
    float4 t1 = *((const float4*)(wsrc + 4));
    float4 t2 = *((const float4*)(wsrc + 8));
    float4 t3 = *((const float4*)(wsrc + 12));
    float4 u0 = ((const float4*)(P.projT + w*2048))[tid];
    float4 u1 = ((const float4*)(P.projT + w*2048))[tid + 256];
    int kb = skq*16;
    Wl[(kb+ 0)*68+sr]=t0.x; Wl[(kb+ 1)*68+sr]=t0.y; Wl[(kb+ 2)*68+sr]=t0.z; Wl[(kb+ 3)*68+sr]=t0.w;
    Wl[(kb+ 4)*68+sr]=t1.x; Wl[(kb+ 5)*68+sr]=t1.y; Wl[(kb+ 6)*68+sr]=t1.z; Wl[(kb+ 7)*68+sr]=t1.w;
    Wl[(kb+ 8)*68+sr]=t2.x; Wl[(kb+ 9)*68+sr]=t2.y; Wl[(kb+10)*68+sr]=t2.z; Wl[(kb+11)*68+sr]=t2.w;
    Wl[(kb+12)*68+sr]=t3.x; Wl[(kb+13)*68+sr]=t3.y; Wl[(kb+14)*68+sr]=t3.z; Wl[(kb+15)*68+sr]=t3.w;
    ((float4*)pl)[tid]       = u0;
    ((float4*)pl)[tid + 256] = u1;
    __syncthreads();
#pragma unroll
    for (int kk = 0; kk < 8; kk++) {
      int kl = kp*8 + kk;
      float4 wv0 = *((const float4*)(Wl + kl*68 + vg*8));
      float4 wv1 = *((const float4*)(Wl + kl*68 + vg*8 + 4));
      float4 pv0 = *((const float4*)(pl + kl*32 + bg*8));
      float4 pv1 = *((const float4*)(pl + kl*32 + bg*8 + 4));
      float wa[8] = {wv0.x,wv0.y,wv0.z,wv0.w,wv1.x,wv1.y,wv1.z,wv1.w};
      float pa[8] = {pv0.x,pv0.y,pv0.z,pv0.w,pv1.x,pv1.y,pv1.z,pv1.w};
#pragma unroll
      for (int i = 0; i < 8; i++)
#pragma unroll
        for (int j = 0; j < 8; j++)
          acc[i*8+j] += wa[i]*pa[j];
    }
  }
  // merge 8 k-slices into part[32][68]
  __syncthreads();
  if (kp == 0) {
#pragma unroll
    for (int j = 0; j < 8; j++) {
      int b = bg*8 + j;
      *((float4*)(part + b*68 + vg*8))     = make_float4(acc[0*8+j], acc[1*8+j], acc[2*8+j], acc[3*8+j]);
      *((float4*)(part + b*68 + vg*8 + 4)) = make_float4(acc[4*8+j], acc[5*8+j], acc[6*8+j], acc[7*8+j]);
    }
  }
  __syncthreads();
  for (int rd = 1; rd < 8; rd++) {
    if (kp == rd) {
#pragma unroll
      for (int j = 0; j < 8; j++) {
        int b = bg*8 + j;
        float4* q0 = (float4*)(part + b*68 + vg*8);
        float4* q1 = q0 + 1;
        float4 a0 = *q0, a1 = *q1;
        a0.x += acc[0*8+j]; a0.y += acc[1*8+j]; a0.z += acc[2*8+j]; a0.w += acc[3*8+j];
        a1.x += acc[4*8+j]; a1.y += acc[5*8+j]; a1.z += acc[6*8+j]; a1.w += acc[7*8+j];
        *q0 = a0; *q1 = a1;
      }
    }
    __syncthreads();
  }
  // final: logits write (coalesced) + online partials; thread = (b, vq)
  int b = tid >> 3, vq = tid & 7;
  float4 pA = *((const float4*)(part + b*68 + vq*8));
  float4 pB = *((const float4*)(part + b*68 + vq*8 + 4));
  int vb = v0 + vq*8;
  float x[8] = {pA.x,pA.y,pA.z,pA.w,pB.x,pB.y,pB.z,pB.w};
#pragma unroll
  for (int i = 0; i < 8; i++) x[i] += P.b_proj[vb + i];
  *((float4*)(P.logits + (size_t)b*V_ + vb))     = make_float4(x[0],x[1],x[2],x[3]);
  *((float4*)(P.logits + (size_t)b*V_ + vb + 4)) = make_float4(x[4],x[5],x[6],x[7]);
  float m = x[0], s = 1.f; int mi = vb;
#pragma unroll
  for (int i = 1; i < 8; i++) {
    if (x[i] > m) { s = s*expf(m - x[i]) + 1.f; m = x[i]; mi = vb + i; }
    else          { s += expf(x[i] - m); }     // ties keep earlier v
  }
  float* rm = sm + 8576; float* rs = sm + 8832; int* ri = (int*)(sm + 9088);
  rm[vq*32 + b] = m; rs[vq*32 + b] = s; ri[vq*32 + b] = mi;
  __syncthreads();
  if (tid < 32) {
    int bb = tid;
    float M = rm[bb], S = rs[bb]; int I = ri[bb];
#pragma unroll
    for (int g = 1; g < 8; g++) {          // ascending v groups
      float m2 = rm[g*32+bb], s2 = rs[g*32+bb]; int i2 = ri[g*32+bb];
      if (m2 > M)       { S = S*expf(M - m2) + s2; M = m2; I = i2; }
      else if (m2 == M) { S += s2; I = min(I, i2); }
      else              { S += s2*expf(m2 - M); }
    }
    P.pm[bid*32 + bb] = M; P.ps[bid*32 + bb] = S; P.pidx[bid*32 + bb] = I;
  }
}

// ---------------- P6: merge chunk partials -> lse[b], idx[b]  (blocks 0..31)
__device__ __forceinline__ void phase6(const DecArgs& P, int bid, int tid, float* smem) {
  if (bid >= B_) return;
  float* sfm = smem; float* sfs = smem + 256; int* sii = (int*)(smem + 512);
  int b = bid;
  float M = P.pm[tid*32 + b], S = P.ps[tid*32 + b]; int I = P.pidx[tid*32 + b];
  int c2 = tid + 256;
  if (c2 < NCHUNK) {
    float m2 = P.pm[c2*32+b], s2 = P.ps[c2*32+b]; int i2 = P.pidx[c2*32+b];
    if (m2 > M)       { S = S*expf(M - m2) + s2; M = m2; I = i2; }
    else if (m2 == M) { S += s2; I = min(I, i2); }
    else              { S += s2*expf(m2 - M); }
  }
  sfm[tid] = M; sfs[tid] = S; sii[tid] = I;
  __syncthreads();
  for (int st = 128; st > 0; st >>= 1) {
    if (tid < st) {
      float m1 = sfm[tid], s1 = sfs[tid]; int i1 = sii[tid];
      float m2 = sfm[tid+st], s2 = sfs[tid+st]; int i2 = sii[tid+st];
      float Mn, Sn; int In;
      if (m2 > m1)      { Mn = m2; Sn = s1*expf(m1-m2) + s2; In = i2; }
      else if (m2 < m1) { Mn = m1; Sn = s1 + s2*expf(m2-m1); In = i1; }
      else              { Mn = m1; Sn = s1 + s2; In = min(i1, i2); }
      sfm[tid] = Mn; sfs[tid] = Sn; sii[tid] = In;
    }
    __syncthreads();
  }
  if (tid == 0) { P.lse[b] = sfm[0] + logf(sfs[0]); P.idx[b] = sii[0]; }
}

// ---------------- final out write (step L-1), 512 blocks
__device__ __forceinline__ void phase_out_final(const DecArgs& P, int bid, int tid) {
  int b = bid & 31, ts = bid >> 5;
  float l = P.lse[b];
  const float4* lg = (const float4*)(P.logits + (size_t)b*V_ + ts*2000);
  float4* o4 = (float4*)(P.out + ((size_t)b*P.L + (P.L-1))*V_ + ts*2000);
  for (int i = tid; i < 500; i += 256) {
    float4 x = lg[i];
    o4[i] = make_float4(x.x-l, x.y-l, x.z-l, x.w-l);
  }
}

__global__ __launch_bounds__(256, 2) void k_decode(DecArgs P) {
  const int bid = blockIdx.x, tid = threadIdx.x;
  __shared__ float sm[12416];

  // init: h, c, idx, wqT transpose
  int g = bid*256 + tid;
  if (g < B_*H_) { P.hA[g] = P.h00[g & (H_-1)]; P.c[g] = P.c00[g & (H_-1)]; }
  if (g < A_*H_) { int k = g >> 7, a = g & 127; P.wqT[g] = P.Wq[a*H_ + k]; }
  if (g < B_) P.idx[g] = 0;
  gbar(P.bar);

  // prologue attend with h0
  phase2(P, P.hA, bid, tid, sm, -1);
  gbar(P.bar);
  phase3(P, bid, tid, sm);
  gbar(P.bar);

  for (int s = 0; s < P.L; s++) {
    const float* hin  = (s & 1) ? P.hB : P.hA;
    float*       hout = (s & 1) ? P.hA : P.hB;
    phase1(P, hin, hout, bid, tid, sm);
    gbar(P.bar);
    phase2(P, hout, bid, tid, sm, s - 1);
    gbar(P.bar);
    phase3(P, bid, tid, sm);
    gbar(P.bar);
    phase4(P, bid, tid);
    gbar(P.bar);
    phase5(P, bid, tid, sm);
    gbar(P.bar);
    phase6(P, bid, tid, sm);
    gbar(P.bar);
  }
  phase_out_final(P, bid, tid);
}

extern "C" void kernel_launch(void* const* d_in, const int* in_sizes, int n_in,
                              void* d_out, int out_size, void* d_ws, size_t ws_size,
                              hipStream_t stream) {
  DecArgs P;
  P.key      = (const float*)d_in[0];
  P.value    = (const float*)d_in[1];
  P.src_lens = (const int*)d_in[4];
  P.W_emb    = (const float*)d_in[5];
  P.b_proj   = (const float*)d_in[6];
  P.Wq       = (const float*)d_in[7];
  P.bq       = (const float*)d_in[8];
  P.W_ih     = (const float*)d_in[9];
  P.W_hh     = (const float*)d_in[10];
  P.b_ih     = (const float*)d_in[11];
  P.b_hh     = (const float*)d_in[12];
  P.Wm       = (const float*)d_in[13];
  P.bm       = (const float*)d_in[14];
  P.h00      = (const float*)d_in[15];
  P.c00      = (const float*)d_in[16];
  P.out      = (float*)d_out;
  P.L        = in_sizes[2] / B_;

  P.bar = (int*)d_ws;                       // 2048 ints reserved
  float* ws = (float*)d_ws + 2048;
  P.hA     = ws; ws += B_*H_;
  P.hB     = ws; ws += B_*H_;
  P.c      = ws; ws += B_*H_;
  P.ctx    = ws; ws += B_*VD_;
  P.en     = ws; ws += B_*T_;
  P.projT  = ws; ws += H_*B_;
  P.lse    = ws; ws += 32;
  P.pm     = ws; ws += NCHUNK*B_;
  P.ps     = ws; ws += NCHUNK*B_;
  P.wqT    = ws; ws += A_*H_;
  P.logits = ws; ws += (size_t)B_*V_;
  P.pidx   = (int*)ws; ws += NCHUNK*B_;
  P.idx    = (int*)ws;

  hipMemsetAsync(P.bar, 0, 2048*sizeof(int), stream);
  hipLaunchKernelGGL(k_decode, dim3(GRID), dim3(256), 0, stream, P);
}

// Round 8
// 22676.086 us; speedup vs baseline: 2.4606x; 2.4606x over previous
//
#include <hip/hip_runtime.h>
#include <math.h>

#define B_  32
#define T_  512
#define H_  512
#define A_  128
#define VD_ 512
#define V_  32000
#define GRID 512
#define NCHUNK 500   // 64-v logits chunks

__device__ __forceinline__ float sigf(float x){ return 1.f/(1.f+expf(-x)); }
__device__ __forceinline__ float dot4(float4 a, float4 b){ return a.x*b.x+a.y*b.y+a.z*b.z+a.w*b.w; }

struct DecArgs {
  const float *key, *value, *W_emb, *b_proj, *Wq, *bq, *W_ih, *W_hh, *b_ih, *b_hh, *Wm, *bm, *h00, *c00;
  const int* src_lens;
  float* out;
  float *hA, *hB, *c, *ctx, *projT, *logits, *lse, *pm, *ps;
  int *pidx, *idx;
  int* bar;   // [grp*32] x32 group counters, [1024] master, [1056] gen, [1088] done
  int L;
};

// ---- device-scope barrier v2: release arrivals, RELAXED polling (no inv storm),
// ---- exactly one acquire per block after release observed.
__device__ __forceinline__ void gbar(int* bar) {
  __syncthreads();
  if (threadIdx.x == 0) {
    int* gen = bar + 1056;
    int g = __hip_atomic_load(gen, __ATOMIC_RELAXED, __HIP_MEMORY_SCOPE_AGENT);
    int grp = blockIdx.x & 31;
    int t = __hip_atomic_fetch_add(bar + grp*32, 1, __ATOMIC_RELEASE, __HIP_MEMORY_SCOPE_AGENT);
    bool rel = false;
    if (t == 15) {
      __hip_atomic_store(bar + grp*32, 0, __ATOMIC_RELAXED, __HIP_MEMORY_SCOPE_AGENT);
      int tm = __hip_atomic_fetch_add(bar + 1024, 1, __ATOMIC_ACQ_REL, __HIP_MEMORY_SCOPE_AGENT);
      if (tm == 31) {
        __hip_atomic_store(bar + 1024, 0, __ATOMIC_RELAXED, __HIP_MEMORY_SCOPE_AGENT);
        __hip_atomic_fetch_add(gen, 1, __ATOMIC_RELEASE, __HIP_MEMORY_SCOPE_AGENT);
        rel = true;   // acq_rel above already invalidated this block's caches
      }
    }
    if (!rel) {
      int it = 0;
      while (__hip_atomic_load(gen, __ATOMIC_RELAXED, __HIP_MEMORY_SCOPE_AGENT) == g) {
        __builtin_amdgcn_s_sleep(8);
        if (++it > 4000) {   // safety: fall back to acquire probing
          while (__hip_atomic_load(gen, __ATOMIC_ACQUIRE, __HIP_MEMORY_SCOPE_AGENT) == g)
            __builtin_amdgcn_s_sleep(32);
          break;
        }
      }
      (void)__hip_atomic_load(gen, __ATOMIC_ACQUIRE, __HIP_MEMORY_SCOPE_AGENT); // one inv
    }
  }
  __syncthreads();
}

// ---------------- PA: gates+cell (blocks 0..255) || out[s-1] (blocks 256..511)
__device__ __forceinline__ void phaseA(const DecArgs& P, const float* hin, float* hout,
                                       int bid, int tid, int s, float* sf) {
  if (bid < 256) {
    int g = tid >> 6, tl = (tid >> 5) & 1, b = tid & 31;
    int t = bid*2 + tl;
    int j = g*512 + t;
    const float4* emb = (const float4*)(P.W_emb + (size_t)P.idx[b]*H_);
    const float4* cx  = (const float4*)(P.ctx + b*VD_);
    const float4* hv  = (const float4*)(hin + b*H_);
    const float4* wi  = (const float4*)(P.W_ih + (size_t)j*(H_+VD_));
    const float4* wc  = wi + 128;
    const float4* wh  = (const float4*)(P.W_hh + (size_t)j*H_);
    float acc = P.b_ih[j] + P.b_hh[j];
#pragma unroll 8
    for (int k = 0; k < 128; k++) acc += dot4(wi[k], emb[k]);
#pragma unroll 8
    for (int k = 0; k < 128; k++) acc += dot4(wc[k], cx[k]);
#pragma unroll 8
    for (int k = 0; k < 128; k++) acc += dot4(wh[k], hv[k]);
    sf[(tl*32 + b)*4 + g] = acc;
    __syncthreads();
    if (tid < 64) {
      int tl2 = tid >> 5, b2 = tid & 31;
      int t2 = bid*2 + tl2;
      float gi = sf[(tl2*32+b2)*4+0], gf = sf[(tl2*32+b2)*4+1];
      float gg = sf[(tl2*32+b2)*4+2], go = sf[(tl2*32+b2)*4+3];
      float c0 = P.c[b2*H_ + t2];
      float c1 = sigf(gf)*c0 + sigf(gi)*tanhf(gg);
      P.c[b2*H_ + t2] = c1;
      hout[b2*H_ + t2] = sigf(go)*tanhf(c1);
    }
  } else if (s > 0) {
    int r = bid - 256;
    int bb = r >> 3, vs = r & 7;
    float l = P.lse[bb];
    const float4* lg = (const float4*)(P.logits + (size_t)bb*V_ + vs*4000);
    float4* o4 = (float4*)(P.out + ((size_t)bb*P.L + (s-1))*V_ + vs*4000);
    for (int i = tid; i < 1000; i += 256) {
      float4 x = lg[i];
      o4[i] = make_float4(x.x-l, x.y-l, x.z-l, x.w-l);
    }
  }
}

// ---------------- PB: q + energy + masked softmax + ctx 64-col slice (blocks 0..255)
// block = vs*32 + b ; vs 0..7  (R3-proven structure)
__device__ __forceinline__ void phaseB(const DecArgs& P, const float* hsrc,
                                       int bid, int tid, float* sf) {
  if (bid >= 256) return;
  int b = bid & 31, vs = bid >> 5;
  float* h_sh   = sf;         // 512
  float* q_sh   = sf + 512;   // 128
  float* red    = sf + 640;   // 256
  float* att_sh = sf + 896;   // 512
  h_sh[tid]       = hsrc[b*H_ + tid];
  h_sh[tid + 256] = hsrc[b*H_ + tid + 256];
  __syncthreads();
  if (tid < 128) {
    const float4* hv = (const float4*)h_sh;
    const float4* w  = (const float4*)(P.Wq + (size_t)tid*H_);
    float acc = P.bq[tid];
#pragma unroll 8
    for (int k = 0; k < 128; k++) acc += dot4(w[k], hv[k]);
    q_sh[tid] = acc;
  }
  __syncthreads();
  const float* kp = P.key + (size_t)b*A_*T_;
  float e0 = 0.f, e1 = 0.f;
#pragma unroll 8
  for (int a = 0; a < A_; a++) {
    float qa = q_sh[a];
    e0 += qa * kp[a*T_ + tid];
    e1 += qa * kp[a*T_ + tid + 256];
  }
  red[tid] = fmaxf(e0, e1);
  __syncthreads();
  for (int s2 = 128; s2 > 0; s2 >>= 1) { if (tid < s2) red[tid] = fmaxf(red[tid], red[tid+s2]); __syncthreads(); }
  float M = red[0];
  __syncthreads();
  int len = P.src_lens[b];
  float p0 = (tid       < len) ? expf(e0 - M) : 0.f;
  float p1 = (tid + 256 < len) ? expf(e1 - M) : 0.f;
  red[tid] = p0 + p1;
  __syncthreads();
  for (int s2 = 128; s2 > 0; s2 >>= 1) { if (tid < s2) red[tid] += red[tid+s2]; __syncthreads(); }
  float S = red[0];
  __syncthreads();
  att_sh[tid]       = p0 / S;
  att_sh[tid + 256] = p1 / S;
  __syncthreads();
  int vl = tid & 63, tq = tid >> 6;
  int v = vs*64 + vl;
  const float* vp = P.value + (size_t)b*T_*VD_ + v;
  float acc = 0.f;
  int t0 = tq*128;
#pragma unroll 8
  for (int t = t0; t < t0 + 128; t++) acc += att_sh[t] * vp[(size_t)t*VD_];
  red[tid] = acc;
  __syncthreads();
  if (tid < 64) P.ctx[b*VD_ + vs*64 + tid] = red[tid] + red[tid+64] + red[tid+128] + red[tid+192];
}

// ---------------- PC: projT[m*32+b] = leaky_relu([c1,ctx1]@Wm[m] + bm)  (blocks 0..63)
__device__ __forceinline__ void phaseC(const DecArgs& P, int bid, int tid) {
  if (bid < 64) {
    int m = bid*8 + (tid>>5), b = tid & 31;
    const float4* cv = (const float4*)(P.c + b*H_);
    const float4* xv = (const float4*)(P.ctx + b*VD_);
    const float4* wa = (const float4*)(P.Wm + (size_t)m*(H_+VD_));
    const float4* wb = wa + 128;
    float acc = P.bm[m];
#pragma unroll 8
    for (int k = 0; k < 128; k++) acc += dot4(wa[k], cv[k]);
#pragma unroll 8
    for (int k = 0; k < 128; k++) acc += dot4(wb[k], xv[k]);
    P.projT[m*32 + b] = (acc > 0.f) ? acc : 0.01f*acc;
  }
}

// ---------------- merge all chunk partials -> lse/idx (run by ONE block, 256 thr)
__device__ __forceinline__ void merge_all(const DecArgs& P, int tid, float* sm) {
  int b = tid >> 3, g = tid & 7;
  float M = -INFINITY, S = 0.f; int I = 0x7fffffff;
  for (int ch = g; ch < NCHUNK; ch += 8) {       // ascending chunk order per lane
    float m2 = P.pm[ch*32+b], s2 = P.ps[ch*32+b]; int i2 = P.pidx[ch*32+b];
    if (m2 > M)       { S = S*expf(M-m2) + s2; M = m2; I = i2; }
    else if (m2 == M) { S += s2; I = min(I, i2); }
    else              { S += s2*expf(m2-M); }
  }
  float* mm = sm; float* ss = sm + 256; int* ii = (int*)(sm + 512);
  mm[tid] = M; ss[tid] = S; ii[tid] = I;
  __syncthreads();
  if (g == 0) {
    for (int j = 1; j < 8; j++) {
      float m2 = mm[b*8+j], s2 = ss[b*8+j]; int i2 = ii[b*8+j];
      if (m2 > M)       { S = S*expf(M-m2) + s2; M = m2; I = i2; }
      else if (m2 == M) { S += s2; I = min(I, i2); }
      else              { S += s2*expf(m2-M); }
    }
    P.lse[b] = M + logf(S);
    P.idx[b] = I;
  }
}

// ---------------- PD: logits chunk (64 v) reg-tiled GEMM + partials + in-phase merge
__device__ __forceinline__ void phaseD(const DecArgs& P, int bid, int tid, float* sm) {
  if (bid >= NCHUNK) return;
  const int v0 = bid * 64;
  float* Wl   = sm;            // [64k][68]
  float* pl   = sm + 4352;     // [64k][32]
  float* part = sm + 6400;     // [32b][68]
  const int kp = tid >> 5, vg = (tid >> 2) & 7, bg = tid & 3;
  const int sr = tid >> 2, skq = tid & 3;
  float acc[64];
#pragma unroll
  for (int i = 0; i < 64; i++) acc[i] = 0.f;

  for (int w = 0; w < 8; w++) {
    __syncthreads();
    const float* wsrc = P.W_emb + (size_t)(v0 + sr)*H_ + w*64 + skq*16;
    float4 t0 = *((const float4*)(wsrc + 0));
    float4 t1 = *((const float4*)(wsrc + 4));
    float4 t2 = *((const float4*)(wsrc + 8));
    float4 t3 = *((const float4*)(wsrc + 12));
    float4 u0 = ((const float4*)(P.projT + w*2048))[tid];
    float4 u1 = ((const float4*)(P.projT + w*2048))[tid + 256];
    int kb = skq*16;
    Wl[(kb+ 0)*68+sr]=t0.x; Wl[(kb+ 1)*68+sr]=t0.y; Wl[(kb+ 2)*68+sr]=t0.z; Wl[(kb+ 3)*68+sr]=t0.w;
    Wl[(kb+ 4)*68+sr]=t1.x; Wl[(kb+ 5)*68+sr]=t1.y; Wl[(kb+ 6)*68+sr]=t1.z; Wl[(kb+ 7)*68+sr]=t1.w;
    Wl[(kb+ 8)*68+sr]=t2.x; Wl[(kb+ 9)*68+sr]=t2.y; Wl[(kb+10)*68+sr]=t2.z; Wl[(kb+11)*68+sr]=t2.w;
    Wl[(kb+12)*68+sr]=t3.x; Wl[(kb+13)*68+sr]=t3.y; Wl[(kb+14)*68+sr]=t3.z; Wl[(kb+15)*68+sr]=t3.w;
    ((float4*)pl)[tid]       = u0;
    ((float4*)pl)[tid + 256] = u1;
    __syncthreads();
#pragma unroll
    for (int kk = 0; kk < 8; kk++) {
      int kl = kp*8 + kk;
      float4 wv0 = *((const float4*)(Wl + kl*68 + vg*8));
      float4 wv1 = *((const float4*)(Wl + kl*68 + vg*8 + 4));
      float4 pv0 = *((const float4*)(pl + kl*32 + bg*8));
      float4 pv1 = *((const float4*)(pl + kl*32 + bg*8 + 4));
      float wa[8] = {wv0.x,wv0.y,wv0.z,wv0.w,wv1.x,wv1.y,wv1.z,wv1.w};
      float pa[8] = {pv0.x,pv0.y,pv0.z,pv0.w,pv1.x,pv1.y,pv1.z,pv1.w};
#pragma unroll
      for (int i = 0; i < 8; i++)
#pragma unroll
        for (int j = 0; j < 8; j++)
          acc[i*8+j] += wa[i]*pa[j];
    }
  }
  __syncthreads();
  if (kp == 0) {
#pragma unroll
    for (int j = 0; j < 8; j++) {
      int b = bg*8 + j;
      *((float4*)(part + b*68 + vg*8))     = make_float4(acc[0*8+j], acc[1*8+j], acc[2*8+j], acc[3*8+j]);
      *((float4*)(part + b*68 + vg*8 + 4)) = make_float4(acc[4*8+j], acc[5*8+j], acc[6*8+j], acc[7*8+j]);
    }
  }
  __syncthreads();
  for (int rd = 1; rd < 8; rd++) {
    if (kp == rd) {
#pragma unroll
      for (int j = 0; j < 8; j++) {
        int b = bg*8 + j;
        float4* q0 = (float4*)(part + b*68 + vg*8);
        float4* q1 = q0 + 1;
        float4 a0 = *q0, a1 = *q1;
        a0.x += acc[0*8+j]; a0.y += acc[1*8+j]; a0.z += acc[2*8+j]; a0.w += acc[3*8+j];
        a1.x += acc[4*8+j]; a1.y += acc[5*8+j]; a1.z += acc[6*8+j]; a1.w += acc[7*8+j];
        *q0 = a0; *q1 = a1;
      }
    }
    __syncthreads();
  }
  int b = tid >> 3, vq = tid & 7;
  float4 pA = *((const float4*)(part + b*68 + vq*8));
  float4 pB = *((const float4*)(part + b*68 + vq*8 + 4));
  int vb = v0 + vq*8;
  float x[8] = {pA.x,pA.y,pA.z,pA.w,pB.x,pB.y,pB.z,pB.w};
#pragma unroll
  for (int i = 0; i < 8; i++) x[i] += P.b_proj[vb + i];
  *((float4*)(P.logits + (size_t)b*V_ + vb))     = make_float4(x[0],x[1],x[2],x[3]);
  *((float4*)(P.logits + (size_t)b*V_ + vb + 4)) = make_float4(x[4],x[5],x[6],x[7]);
  float m = x[0], s = 1.f; int mi = vb;
#pragma unroll
  for (int i = 1; i < 8; i++) {
    if (x[i] > m) { s = s*expf(m - x[i]) + 1.f; m = x[i]; mi = vb + i; }
    else          { s += expf(x[i] - m); }
  }
  float* rm = sm + 8576; float* rs = sm + 8832; int* ri = (int*)(sm + 9088);
  rm[vq*32 + b] = m; rs[vq*32 + b] = s; ri[vq*32 + b] = mi;
  __syncthreads();
  if (tid < 32) {
    int bb = tid;
    float M = rm[bb], S = rs[bb]; int I = ri[bb];
#pragma unroll
    for (int g = 1; g < 8; g++) {
      float m2 = rm[g*32+bb], s2 = rs[g*32+bb]; int i2 = ri[g*32+bb];
      if (m2 > M)       { S = S*expf(M - m2) + s2; M = m2; I = i2; }
      else if (m2 == M) { S += s2; I = min(I, i2); }
      else              { S += s2*expf(m2 - M); }
    }
    P.pm[bid*32 + bb] = M; P.ps[bid*32 + bb] = S; P.pidx[bid*32 + bb] = I;
  }
  // ---- in-phase merge: last chunk block to finish merges all partials
  __syncthreads();
  if (tid == 0) {
    int dc = __hip_atomic_fetch_add(P.bar + 1088, 1, __ATOMIC_ACQ_REL, __HIP_MEMORY_SCOPE_AGENT);
    ((int*)sm)[0] = (dc == NCHUNK - 1) ? 1 : 0;
  }
  __syncthreads();
  int last = ((int*)sm)[0];
  __syncthreads();
  if (last) {
    merge_all(P, tid, sm);
    __syncthreads();
    if (tid == 0) __hip_atomic_store(P.bar + 1088, 0, __ATOMIC_RELAXED, __HIP_MEMORY_SCOPE_AGENT);
  }
}

// ---------------- final out write (step L-1), 512 blocks
__device__ __forceinline__ void phase_out_final(const DecArgs& P, int bid, int tid) {
  int b = bid & 31, ts = bid >> 5;
  float l = P.lse[b];
  const float4* lg = (const float4*)(P.logits + (size_t)b*V_ + ts*2000);
  float4* o4 = (float4*)(P.out + ((size_t)b*P.L + (P.L-1))*V_ + ts*2000);
  for (int i = tid; i < 500; i += 256) {
    float4 x = lg[i];
    o4[i] = make_float4(x.x-l, x.y-l, x.z-l, x.w-l);
  }
}

__global__ __launch_bounds__(256, 2) void k_decode(DecArgs P) {
  const int bid = blockIdx.x, tid = threadIdx.x;
  __shared__ float sm[9600];   // 38.4 KB

  int g = bid*256 + tid;
  if (g < B_*H_) { P.hA[g] = P.h00[g & (H_-1)]; P.c[g] = P.c00[g & (H_-1)]; }
  if (g < B_) P.idx[g] = 0;
  gbar(P.bar);

  phaseB(P, P.hA, bid, tid, sm);   // prologue attend with h0
  gbar(P.bar);

  for (int s = 0; s < P.L; s++) {
    const float* hin  = (s & 1) ? P.hB : P.hA;
    float*       hout = (s & 1) ? P.hA : P.hB;
    phaseA(P, hin, hout, bid, tid, s, sm);
    gbar(P.bar);
    phaseB(P, hout, bid, tid, sm);
    gbar(P.bar);
    phaseC(P, bid, tid);
    gbar(P.bar);
    phaseD(P, bid, tid, sm);
    gbar(P.bar);
  }
  phase_out_final(P, bid, tid);
}

extern "C" void kernel_launch(void* const* d_in, const int* in_sizes, int n_in,
                              void* d_out, int out_size, void* d_ws, size_t ws_size,
                              hipStream_t stream) {
  DecArgs P;
  P.key      = (const float*)d_in[0];
  P.value    = (const float*)d_in[1];
  P.src_lens = (const int*)d_in[4];
  P.W_emb    = (const float*)d_in[5];
  P.b_proj   = (const float*)d_in[6];
  P.Wq       = (const float*)d_in[7];
  P.bq       = (const float*)d_in[8];
  P.W_ih     = (const float*)d_in[9];
  P.W_hh     = (const float*)d_in[10];
  P.b_ih     = (const float*)d_in[11];
  P.b_hh     = (const float*)d_in[12];
  P.Wm       = (const float*)d_in[13];
  P.bm       = (const float*)d_in[14];
  P.h00      = (const float*)d_in[15];
  P.c00      = (const float*)d_in[16];
  P.out      = (float*)d_out;
  P.L        = in_sizes[2] / B_;

  P.bar = (int*)d_ws;                       // 2048 ints reserved
  float* ws = (float*)d_ws + 2048;
  P.hA     = ws; ws += B_*H_;
  P.hB     = ws; ws += B_*H_;
  P.c      = ws; ws += B_*H_;
  P.ctx    = ws; ws += B_*VD_;
  P.projT  = ws; ws += H_*B_;
  P.lse    = ws; ws += 32;
  P.pm     = ws; ws += NCHUNK*B_;
  P.ps     = ws; ws += NCHUNK*B_;
  P.logits = ws; ws += (size_t)B_*V_;
  P.pidx   = (int*)ws; ws += NCHUNK*B_;
  P.idx    = (int*)ws;

  hipMemsetAsync(P.bar, 0, 2048*sizeof(int), stream);
  hipLaunchKernelGGL(k_decode, dim3(GRID), dim3(256), 0, stream, P);
}